// Round 9
// baseline (74.758 us; speedup 1.0000x reference)
//
#include <hip/hip_runtime.h>

constexpr int N = 8192;
// MIN_DIST = RADIUS*2*scale = 1.0f;  TRI = N(N+1)/2, exact in f32
constexpr float TRI = 33558528.0f;
constexpr int MAIN_BLOCKS = 2048;

__device__ __forceinline__ float fsqrt(float v) { return __builtin_amdgcn_sqrtf(v); }

// ws layout: p4[N] | row_sd[N] | row_sm[N] | row_corr[N] | partials[64] | counter

// 32 blocks: pack the interleaved stream AND the O(N) loss terms; block 0 also
// zeroes the completion counter (re-armed every call, before main launches).
__global__ __launch_bounds__(256)
void pack_kernel(const float* __restrict__ x, const float* __restrict__ y,
                 const float* __restrict__ z, float4* __restrict__ p4,
                 float* __restrict__ partials, unsigned* __restrict__ counter) {
    const int tid = threadIdx.x;
    const int i   = blockIdx.x * 256 + tid;
    if (i == 0) *counter = 0u;

    const float yv = y[i], zv = z[i];
    p4[i] = make_float4(x[i], yv, zv, 0.f);

    float fix = fmaxf(yv - 1.f, 0.f) + fmaxf(-1.f - yv, 0.f)
              + fmaxf(zv - 1.f, 0.f) + fmaxf(-1.f - zv, 0.f);
    float noise = 0.f;
    if (i < N - 2) {
        const float d2y = y[i + 2] - 2.f * y[i + 1] + y[i];
        const float d2z = z[i + 2] - 2.f * z[i + 1] + z[i];
        noise = d2y * d2y + d2z * d2z;
    }
    const int lane = tid & 63, wave = tid >> 6;
    __shared__ float s[4][2];
    for (int off = 32; off; off >>= 1) {
        fix   += __shfl_down(fix, off);
        noise += __shfl_down(noise, off);
    }
    if (lane == 0) { s[wave][0] = fix; s[wave][1] = noise; }
    __syncthreads();
    if (tid == 0) {
        partials[blockIdx.x * 2]     = s[0][0] + s[1][0] + s[2][0] + s[3][0];
        partials[blockIdx.x * 2 + 1] = s[0][1] + s[1][1] + s[2][1] + s[3][1];
    }
}

// 2048 blocks:
//  [0,1024):    pair tiles — rows {4b..4b+3} + {N-4b-4..N-4b-1}, j >= i sweep on
//               the packed stream (1 dwordx4 per j per thread, preloaded).
//  [1024,2048): masked-prefix-run correction, 8 rows/block, 2 rows/wave,
//               128-j ballot windows with speculative preload.
//  Last block to finish: device-scope fence + counter; reduces the row arrays
//  and partials, writes out[0].
__global__ __launch_bounds__(256, 8)
void main_kernel(const float4* __restrict__ p4,
                 float* __restrict__ row_sd, float* __restrict__ row_sm,
                 float* __restrict__ row_corr, const float* __restrict__ partials,
                 unsigned* __restrict__ counter, float* __restrict__ out) {
    const int tid  = threadIdx.x;
    const int lane = tid & 63;
    const int wave = tid >> 6;

    if (blockIdx.x < 1024) {
        const int b       = blockIdx.x;
        const int topBase = 4 * b;            // 0..4092
        const int botBase = N - 4 * (b + 1);  // 8188..4096

        float xr[8], yr[8], zr[8];
#pragma unroll
        for (int r = 0; r < 4; ++r) {
            const float4 pt = p4[topBase + r];
            const float4 pb = p4[botBase + r];
            xr[r]     = pt.x; yr[r]     = pt.y; zr[r]     = pt.z;
            xr[4 + r] = pb.x; yr[4 + r] = pb.y; zr[4 + r] = pb.z;
        }
        float sd[8], sm[8];
#pragma unroll
        for (int r = 0; r < 8; ++r) { sd[r] = 0.f; sm[r] = 0.f; }

#pragma unroll
        for (int g = 0; g < 2; ++g) {
            const int base = g ? botBase : topBase;
            const int ro   = g * 4;

            // head chunk [base, base+256): predicated vs diagonal and N
            {
                const int    j  = base + tid;
                const int    jc = (j < N) ? j : (N - 1);
                const float4 p  = p4[jc];
#pragma unroll
                for (int r = 0; r < 4; ++r) {
                    const float dx = p.x - xr[ro + r], dy = p.y - yr[ro + r], dz = p.z - zr[ro + r];
                    const float d  = fsqrt(dx * dx + dy * dy + dz * dz);
                    if (j < N && tid >= r) { sd[ro + r] += d; sm[ro + r] += fminf(d, 1.f); }
                }
            }
            // full middle 256-chunks: predicate-free, preloaded
            int j0 = base + 256;
            if (j0 + 256 <= N) {
                float4 p = p4[j0 + tid];
                while (true) {
                    const float4 c    = p;
                    const bool   more = (j0 + 512 <= N);
                    if (more) p = p4[j0 + 256 + tid];
#pragma unroll
                    for (int r = 0; r < 4; ++r) {
                        const float dx = c.x - xr[ro + r], dy = c.y - yr[ro + r], dz = c.z - zr[ro + r];
                        const float d  = fsqrt(dx * dx + dy * dy + dz * dz);
                        sd[ro + r] += d; sm[ro + r] += fminf(d, 1.f);
                    }
                    j0 += 256;
                    if (!more) break;
                }
            }
            // tail partial chunk
            if (j0 < N) {
                const int j = j0 + tid;
                if (j < N) {
                    const float4 p = p4[j];
#pragma unroll
                    for (int r = 0; r < 4; ++r) {
                        const float dx = p.x - xr[ro + r], dy = p.y - yr[ro + r], dz = p.z - zr[ro + r];
                        const float d  = fsqrt(dx * dx + dy * dy + dz * dz);
                        sd[ro + r] += d; sm[ro + r] += fminf(d, 1.f);
                    }
                }
            }
        }

        __shared__ float lsd[4][8];
        __shared__ float lsm[4][8];
#pragma unroll
        for (int r = 0; r < 8; ++r) {
            float a = sd[r], c = sm[r];
#pragma unroll
            for (int off = 32; off; off >>= 1) {
                a += __shfl_down(a, off);
                c += __shfl_down(c, off);
            }
            if (lane == 0) { lsd[wave][r] = a; lsm[wave][r] = c; }
        }
        __syncthreads();
        if (tid < 8) {
            const float a = lsd[0][tid] + lsd[1][tid] + lsd[2][tid] + lsd[3][tid];
            const float c = lsm[0][tid] + lsm[1][tid] + lsm[2][tid] + lsm[3][tid];
            const int   i = (tid < 4) ? (topBase + tid) : (botBase + tid - 4);
            row_sd[i] = a;
            row_sm[i] = c;
        }
    } else {
        // corr: 8 rows/block, 2 rows/wave, 128-j windows, speculative preload
        const int cb = blockIdx.x - 1024;
#pragma unroll
        for (int rr = 0; rr < 2; ++rr) {
            const int    i  = 8 * cb + 2 * wave + rr;
            const float4 pi = p4[i];
            float corr = 0.f;
            int   jb   = i;
            float4 a  = p4[min(jb + lane,      N - 1)];
            float4 bq = p4[min(jb + 64 + lane, N - 1)];
            while (true) {
                const float4 na = p4[min(jb + 128 + lane, N - 1)];
                const float4 nb = p4[min(jb + 192 + lane, N - 1)];
                const int j0i = jb + lane, j1i = jb + 64 + lane;
                float dx = a.x - pi.x, dy = a.y - pi.y, dz = a.z - pi.z;
                const float d0 = fsqrt(dx * dx + dy * dy + dz * dz);
                dx = bq.x - pi.x; dy = bq.y - pi.y; dz = bq.z - pi.z;
                const float d1 = fsqrt(dx * dx + dy * dy + dz * dz);
                const unsigned long long m0 = __ballot(j0i >= N || d0 > 1.f);
                const unsigned long long m1 = __ballot(j1i >= N || d1 > 1.f);
                int stop;
                if (m0)      stop = __builtin_ctzll(m0);
                else if (m1) stop = 64 + __builtin_ctzll(m1);
                else         stop = 128;
                if (lane < stop)      corr += 1.f - d0;
                if (64 + lane < stop) corr += 1.f - d1;
                if (stop < 128) break;
                jb += 128;
                a = na; bq = nb;
            }
#pragma unroll
            for (int off = 32; off; off >>= 1) corr += __shfl_down(corr, off);
            if (lane == 0) row_corr[i] = corr;
        }
    }

    // ---- last-block finalize ----
    __shared__ unsigned s_old;
    __syncthreads();
    if (tid == 0) {
        __threadfence();
        s_old = atomicAdd(counter, 1u);
    }
    __syncthreads();
    if (s_old == MAIN_BLOCKS - 1) {
        __threadfence();
        float A = 0.f, M = 0.f, C = 0.f;
        for (int i = tid; i < N; i += 256) {
            A += row_sd[i];
            M += row_sm[i];
            C += row_corr[i];
        }
        float fx = 0.f, nz = 0.f;
        if (tid < 32) { fx = partials[tid * 2]; nz = partials[tid * 2 + 1]; }
        __shared__ float s[4][5];
        float v[5] = {A, M, C, fx, nz};
#pragma unroll
        for (int c = 0; c < 5; ++c) {
#pragma unroll
            for (int off = 32; off; off >>= 1) v[c] += __shfl_down(v[c], off);
        }
        if (lane == 0) {
#pragma unroll
            for (int c = 0; c < 5; ++c) s[wave][c] = v[c];
        }
        __syncthreads();
        if (tid == 0) {
            float t[5];
#pragma unroll
            for (int c = 0; c < 5; ++c) t[c] = s[0][c] + s[1][c] + s[2][c] + s[3][c];
            out[0] = t[3] + (2.f * t[0]) / 10000.f
                   + (2.f * (TRI - t[1]) - (float)N - t[2]) + 10.f * t[4];
        }
    }
}

extern "C" void kernel_launch(void* const* d_in, const int* in_sizes, int n_in,
                              void* d_out, int out_size, void* d_ws, size_t ws_size,
                              hipStream_t stream) {
    const float* x = (const float*)d_in[0];
    const float* y = (const float*)d_in[1];
    const float* z = (const float*)d_in[2];
    float* out      = (float*)d_out;
    float4* p4      = (float4*)d_ws;
    float* row_sd   = (float*)(p4 + N);
    float* row_sm   = row_sd + N;
    float* row_corr = row_sm + N;
    float* partials = row_corr + N;
    unsigned* counter = (unsigned*)(partials + 64);

    pack_kernel<<<N / 256, 256, 0, stream>>>(x, y, z, p4, partials, counter);
    main_kernel<<<MAIN_BLOCKS, 256, 0, stream>>>(p4, row_sd, row_sm, row_corr,
                                                 partials, counter, out);
}

// Round 10
// 73.657 us; speedup vs baseline: 1.0149x; 1.0149x over previous
//
#include <hip/hip_runtime.h>

constexpr int N = 8192;
// MIN_DIST = RADIUS*2*scale = 1.0f;  TRI = N(N+1)/2, exact in f32
constexpr float TRI = 33558528.0f;
constexpr int MAIN_BLOCKS = 2048;

__device__ __forceinline__ float fsqrt(float v) { return __builtin_amdgcn_sqrtf(v); }

// ws layout: p4[N] | row_sd[N] | row_sm[N] | row_corr[N] | partials[64] | counter

// 32 blocks: pack the interleaved stream AND the O(N) loss terms; block 0 also
// zeroes the completion counter (re-armed every call, before main launches).
__global__ __launch_bounds__(256)
void pack_kernel(const float* __restrict__ x, const float* __restrict__ y,
                 const float* __restrict__ z, float4* __restrict__ p4,
                 float* __restrict__ partials, unsigned* __restrict__ counter) {
    const int tid = threadIdx.x;
    const int i   = blockIdx.x * 256 + tid;
    if (i == 0) *counter = 0u;

    const float yv = y[i], zv = z[i];
    p4[i] = make_float4(x[i], yv, zv, 0.f);

    float fix = fmaxf(yv - 1.f, 0.f) + fmaxf(-1.f - yv, 0.f)
              + fmaxf(zv - 1.f, 0.f) + fmaxf(-1.f - zv, 0.f);
    float noise = 0.f;
    if (i < N - 2) {
        const float d2y = y[i + 2] - 2.f * y[i + 1] + y[i];
        const float d2z = z[i + 2] - 2.f * z[i + 1] + z[i];
        noise = d2y * d2y + d2z * d2z;
    }
    const int lane = tid & 63, wave = tid >> 6;
    __shared__ float s[4][2];
    for (int off = 32; off; off >>= 1) {
        fix   += __shfl_down(fix, off);
        noise += __shfl_down(noise, off);
    }
    if (lane == 0) { s[wave][0] = fix; s[wave][1] = noise; }
    __syncthreads();
    if (tid == 0) {
        partials[blockIdx.x * 2]     = s[0][0] + s[1][0] + s[2][0] + s[3][0];
        partials[blockIdx.x * 2 + 1] = s[0][1] + s[1][1] + s[2][1] + s[3][1];
    }
}

// 2048 blocks:
//  [0,1024):    pair tiles — rows {4b..4b+3} + {N-4b-4..N-4b-1}, j >= i sweep on
//               the packed stream (1 dwordx4 per j per thread, preloaded).
//  [1024,2048): masked-prefix-run correction, 8 rows/block, 2 rows/wave,
//               128-j ballot windows with speculative preload.
//  Last block to finish: device-scope fence + counter; reduces the row arrays
//  and partials, writes out[0].
__global__ __launch_bounds__(256, 8)
void main_kernel(const float4* __restrict__ p4,
                 float* __restrict__ row_sd, float* __restrict__ row_sm,
                 float* __restrict__ row_corr, const float* __restrict__ partials,
                 unsigned* __restrict__ counter, float* __restrict__ out) {
    const int tid  = threadIdx.x;
    const int lane = tid & 63;
    const int wave = tid >> 6;

    if (blockIdx.x < 1024) {
        const int b       = blockIdx.x;
        const int topBase = 4 * b;            // 0..4092
        const int botBase = N - 4 * (b + 1);  // 8188..4096

        float xr[8], yr[8], zr[8];
#pragma unroll
        for (int r = 0; r < 4; ++r) {
            const float4 pt = p4[topBase + r];
            const float4 pb = p4[botBase + r];
            xr[r]     = pt.x; yr[r]     = pt.y; zr[r]     = pt.z;
            xr[4 + r] = pb.x; yr[4 + r] = pb.y; zr[4 + r] = pb.z;
        }
        float sd[8], sm[8];
#pragma unroll
        for (int r = 0; r < 8; ++r) { sd[r] = 0.f; sm[r] = 0.f; }

#pragma unroll
        for (int g = 0; g < 2; ++g) {
            const int base = g ? botBase : topBase;
            const int ro   = g * 4;

            // head chunk [base, base+256): predicated vs diagonal and N
            {
                const int    j  = base + tid;
                const int    jc = (j < N) ? j : (N - 1);
                const float4 p  = p4[jc];
#pragma unroll
                for (int r = 0; r < 4; ++r) {
                    const float dx = p.x - xr[ro + r], dy = p.y - yr[ro + r], dz = p.z - zr[ro + r];
                    const float d  = fsqrt(dx * dx + dy * dy + dz * dz);
                    if (j < N && tid >= r) { sd[ro + r] += d; sm[ro + r] += fminf(d, 1.f); }
                }
            }
            // full middle 256-chunks: predicate-free, preloaded
            int j0 = base + 256;
            if (j0 + 256 <= N) {
                float4 p = p4[j0 + tid];
                while (true) {
                    const float4 c    = p;
                    const bool   more = (j0 + 512 <= N);
                    if (more) p = p4[j0 + 256 + tid];
#pragma unroll
                    for (int r = 0; r < 4; ++r) {
                        const float dx = c.x - xr[ro + r], dy = c.y - yr[ro + r], dz = c.z - zr[ro + r];
                        const float d  = fsqrt(dx * dx + dy * dy + dz * dz);
                        sd[ro + r] += d; sm[ro + r] += fminf(d, 1.f);
                    }
                    j0 += 256;
                    if (!more) break;
                }
            }
            // tail partial chunk
            if (j0 < N) {
                const int j = j0 + tid;
                if (j < N) {
                    const float4 p = p4[j];
#pragma unroll
                    for (int r = 0; r < 4; ++r) {
                        const float dx = p.x - xr[ro + r], dy = p.y - yr[ro + r], dz = p.z - zr[ro + r];
                        const float d  = fsqrt(dx * dx + dy * dy + dz * dz);
                        sd[ro + r] += d; sm[ro + r] += fminf(d, 1.f);
                    }
                }
            }
        }

        __shared__ float lsd[4][8];
        __shared__ float lsm[4][8];
#pragma unroll
        for (int r = 0; r < 8; ++r) {
            float a = sd[r], c = sm[r];
#pragma unroll
            for (int off = 32; off; off >>= 1) {
                a += __shfl_down(a, off);
                c += __shfl_down(c, off);
            }
            if (lane == 0) { lsd[wave][r] = a; lsm[wave][r] = c; }
        }
        __syncthreads();
        if (tid < 8) {
            const float a = lsd[0][tid] + lsd[1][tid] + lsd[2][tid] + lsd[3][tid];
            const float c = lsm[0][tid] + lsm[1][tid] + lsm[2][tid] + lsm[3][tid];
            const int   i = (tid < 4) ? (topBase + tid) : (botBase + tid - 4);
            row_sd[i] = a;
            row_sm[i] = c;
        }
    } else {
        // corr: 8 rows/block, 2 rows/wave, 128-j windows, speculative preload
        const int cb = blockIdx.x - 1024;
#pragma unroll
        for (int rr = 0; rr < 2; ++rr) {
            const int    i  = 8 * cb + 2 * wave + rr;
            const float4 pi = p4[i];
            float corr = 0.f;
            int   jb   = i;
            float4 a  = p4[min(jb + lane,      N - 1)];
            float4 bq = p4[min(jb + 64 + lane, N - 1)];
            while (true) {
                const float4 na = p4[min(jb + 128 + lane, N - 1)];
                const float4 nb = p4[min(jb + 192 + lane, N - 1)];
                const int j0i = jb + lane, j1i = jb + 64 + lane;
                float dx = a.x - pi.x, dy = a.y - pi.y, dz = a.z - pi.z;
                const float d0 = fsqrt(dx * dx + dy * dy + dz * dz);
                dx = bq.x - pi.x; dy = bq.y - pi.y; dz = bq.z - pi.z;
                const float d1 = fsqrt(dx * dx + dy * dy + dz * dz);
                const unsigned long long m0 = __ballot(j0i >= N || d0 > 1.f);
                const unsigned long long m1 = __ballot(j1i >= N || d1 > 1.f);
                int stop;
                if (m0)      stop = __builtin_ctzll(m0);
                else if (m1) stop = 64 + __builtin_ctzll(m1);
                else         stop = 128;
                if (lane < stop)      corr += 1.f - d0;
                if (64 + lane < stop) corr += 1.f - d1;
                if (stop < 128) break;
                jb += 128;
                a = na; bq = nb;
            }
#pragma unroll
            for (int off = 32; off; off >>= 1) corr += __shfl_down(corr, off);
            if (lane == 0) row_corr[i] = corr;
        }
    }

    // ---- last-block finalize ----
    __shared__ unsigned s_old;
    __syncthreads();
    if (tid == 0) {
        __threadfence();
        s_old = atomicAdd(counter, 1u);
    }
    __syncthreads();
    if (s_old == MAIN_BLOCKS - 1) {
        __threadfence();
        float A = 0.f, M = 0.f, C = 0.f;
        for (int i = tid; i < N; i += 256) {
            A += row_sd[i];
            M += row_sm[i];
            C += row_corr[i];
        }
        float fx = 0.f, nz = 0.f;
        if (tid < 32) { fx = partials[tid * 2]; nz = partials[tid * 2 + 1]; }
        __shared__ float s[4][5];
        float v[5] = {A, M, C, fx, nz};
#pragma unroll
        for (int c = 0; c < 5; ++c) {
#pragma unroll
            for (int off = 32; off; off >>= 1) v[c] += __shfl_down(v[c], off);
        }
        if (lane == 0) {
#pragma unroll
            for (int c = 0; c < 5; ++c) s[wave][c] = v[c];
        }
        __syncthreads();
        if (tid == 0) {
            float t[5];
#pragma unroll
            for (int c = 0; c < 5; ++c) t[c] = s[0][c] + s[1][c] + s[2][c] + s[3][c];
            out[0] = t[3] + (2.f * t[0]) / 10000.f
                   + (2.f * (TRI - t[1]) - (float)N - t[2]) + 10.f * t[4];
        }
    }
}

extern "C" void kernel_launch(void* const* d_in, const int* in_sizes, int n_in,
                              void* d_out, int out_size, void* d_ws, size_t ws_size,
                              hipStream_t stream) {
    const float* x = (const float*)d_in[0];
    const float* y = (const float*)d_in[1];
    const float* z = (const float*)d_in[2];
    float* out      = (float*)d_out;
    float4* p4      = (float4*)d_ws;
    float* row_sd   = (float*)(p4 + N);
    float* row_sm   = row_sd + N;
    float* row_corr = row_sm + N;
    float* partials = row_corr + N;
    unsigned* counter = (unsigned*)(partials + 64);

    pack_kernel<<<N / 256, 256, 0, stream>>>(x, y, z, p4, partials, counter);
    main_kernel<<<MAIN_BLOCKS, 256, 0, stream>>>(p4, row_sd, row_sm, row_corr,
                                                 partials, counter, out);
}

// Round 11
// 33.826 us; speedup vs baseline: 2.2100x; 2.1775x over previous
//
#include <hip/hip_runtime.h>

constexpr int N = 8192;
// MIN_DIST = RADIUS*2*scale = 1.0f;  TRI = N(N+1)/2, exact in f32
constexpr float TRI = 33558528.0f;

__device__ __forceinline__ float fsqrt(float v) { return __builtin_amdgcn_sqrtf(v); }

// ws layout: p4[N] (float4) | row_sd[N] | row_sm[N] | row_corr[N] | partials[32*5]

__global__ __launch_bounds__(256)
void pack_kernel(const float* __restrict__ x, const float* __restrict__ y,
                 const float* __restrict__ z, float4* __restrict__ p4) {
    const int i = blockIdx.x * 256 + threadIdx.x;
    p4[i] = make_float4(x[i], y[i], z[i], 0.f);
}

// 2048 blocks:
//  [0,1024):    pair tiles — rows {4b..4b+3} (top) + {N-4b-4..N-4b-1} (bot).
//               j >= i sweep over 1024-point tiles staged into LDS with
//               double-buffered global_load_lds; compute reads ds_read_b128.
//  [1024,2048): masked-prefix-run correction (unchanged from R7).
__global__ __launch_bounds__(256, 4)
void main_kernel(const float4* __restrict__ p4,
                 float* __restrict__ row_sd, float* __restrict__ row_sm,
                 float* __restrict__ row_corr) {
    __shared__ float4 buf[2][1024];          // 32 KB double buffer
    const int tid  = threadIdx.x;
    const int lane = tid & 63;
    const int wave = tid >> 6;

    if (blockIdx.x < 1024) {
        const int b       = blockIdx.x;
        const int topBase = 4 * b;            // 0..4092  (tile t0 = topBase>>10 <= 3)
        const int botBase = N - 4 * (b + 1);  // 8188..4096 (tile tb0 >= 4)

        float xr[8], yr[8], zr[8];
#pragma unroll
        for (int r = 0; r < 4; ++r) {
            const float4 pt = p4[topBase + r];
            const float4 pb = p4[botBase + r];
            xr[r]     = pt.x; yr[r]     = pt.y; zr[r]     = pt.z;
            xr[4 + r] = pb.x; yr[4 + r] = pb.y; zr[4 + r] = pb.z;
        }
        float sd[8], sm[8];
#pragma unroll
        for (int r = 0; r < 8; ++r) { sd[r] = 0.f; sm[r] = 0.f; }

        const int t0  = topBase >> 10;   // first tile needed (covers bot range too)
        const int tb0 = botBase >> 10;   // first tile containing bot rows

        // async stage of tile t into buf[s]: 4 x 16B per thread, LDS dest is
        // wave-uniform base + lane*16 (linear layout, matching lane order)
        auto stage = [&](int t, int s) {
#pragma unroll
            for (int q = 0; q < 4; ++q) {
                __builtin_amdgcn_global_load_lds(
                    (const __attribute__((address_space(1))) uint32_t*)(p4 + t * 1024 + q * 256 + tid),
                    (__attribute__((address_space(3))) uint32_t*)(&buf[s][q * 256 + tid]),
                    16, 0, 0);
            }
        };

        int cur = 0;
        stage(t0, 0);
        __syncthreads();                 // drains vmcnt -> buf[0] ready

        for (int t = t0; t < 8; ++t) {
            if (t < 7) stage(t + 1, cur ^ 1);
            const int  tbase  = t << 10;
            const bool hasBot = (t >= tb0);
            const bool pred   = (t == t0) || (t == tb0);
#pragma unroll
            for (int it = 0; it < 4; ++it) {
                const int    idx = (wave << 8) + (it << 6) + lane;  // disjoint per wave
                const float4 c   = buf[cur][idx];
                const int    j   = tbase + idx;
                if (pred) {
#pragma unroll
                    for (int r = 0; r < 4; ++r) {
                        const float dx = c.x - xr[r], dy = c.y - yr[r], dz = c.z - zr[r];
                        const float d  = fsqrt(dx * dx + dy * dy + dz * dz);
                        if (j >= topBase + r) { sd[r] += d; sm[r] += fminf(d, 1.f); }
                    }
                    if (hasBot) {
#pragma unroll
                        for (int r = 0; r < 4; ++r) {
                            const float dx = c.x - xr[4 + r], dy = c.y - yr[4 + r], dz = c.z - zr[4 + r];
                            const float d  = fsqrt(dx * dx + dy * dy + dz * dz);
                            if (j >= botBase + r) { sd[4 + r] += d; sm[4 + r] += fminf(d, 1.f); }
                        }
                    }
                } else {
#pragma unroll
                    for (int r = 0; r < 4; ++r) {
                        const float dx = c.x - xr[r], dy = c.y - yr[r], dz = c.z - zr[r];
                        const float d  = fsqrt(dx * dx + dy * dy + dz * dz);
                        sd[r] += d; sm[r] += fminf(d, 1.f);
                    }
                    if (hasBot) {
#pragma unroll
                        for (int r = 0; r < 4; ++r) {
                            const float dx = c.x - xr[4 + r], dy = c.y - yr[4 + r], dz = c.z - zr[4 + r];
                            const float d  = fsqrt(dx * dx + dy * dy + dz * dz);
                            sd[4 + r] += d; sm[4 + r] += fminf(d, 1.f);
                        }
                    }
                }
            }
            __syncthreads();             // staged tile complete + buf[cur] free
            cur ^= 1;
        }

        // reduce 8 rows across the block
        __shared__ float lsd[4][8];
        __shared__ float lsm[4][8];
#pragma unroll
        for (int r = 0; r < 8; ++r) {
            float a = sd[r], c = sm[r];
#pragma unroll
            for (int off = 32; off; off >>= 1) {
                a += __shfl_down(a, off);
                c += __shfl_down(c, off);
            }
            if (lane == 0) { lsd[wave][r] = a; lsm[wave][r] = c; }
        }
        __syncthreads();
        if (tid < 8) {
            const float a = lsd[0][tid] + lsd[1][tid] + lsd[2][tid] + lsd[3][tid];
            const float c = lsm[0][tid] + lsm[1][tid] + lsm[2][tid] + lsm[3][tid];
            const int   i = (tid < 4) ? (topBase + tid) : (botBase + tid - 4);
            row_sd[i] = a;
            row_sm[i] = c;
        }
    } else {
        // corr: 8 rows/block, 2 rows/wave, 128-j windows, speculative preload
        const int cb = blockIdx.x - 1024;
#pragma unroll
        for (int rr = 0; rr < 2; ++rr) {
            const int    i  = 8 * cb + 2 * wave + rr;
            const float4 pi = p4[i];
            float corr = 0.f;
            int   jb   = i;
            float4 a  = p4[min(jb + lane,      N - 1)];
            float4 bq = p4[min(jb + 64 + lane, N - 1)];
            while (true) {
                const float4 na = p4[min(jb + 128 + lane, N - 1)];
                const float4 nb = p4[min(jb + 192 + lane, N - 1)];
                const int j0i = jb + lane, j1i = jb + 64 + lane;
                float dx = a.x - pi.x, dy = a.y - pi.y, dz = a.z - pi.z;
                const float d0 = fsqrt(dx * dx + dy * dy + dz * dz);
                dx = bq.x - pi.x; dy = bq.y - pi.y; dz = bq.z - pi.z;
                const float d1 = fsqrt(dx * dx + dy * dy + dz * dz);
                const unsigned long long m0 = __ballot(j0i >= N || d0 > 1.f);
                const unsigned long long m1 = __ballot(j1i >= N || d1 > 1.f);
                int stop;
                if (m0)      stop = __builtin_ctzll(m0);
                else if (m1) stop = 64 + __builtin_ctzll(m1);
                else         stop = 128;
                if (lane < stop)      corr += 1.f - d0;
                if (64 + lane < stop) corr += 1.f - d1;
                if (stop < 128) break;
                jb += 128;
                a = na; bq = nb;
            }
#pragma unroll
            for (int off = 32; off; off >>= 1) corr += __shfl_down(corr, off);
            if (lane == 0) row_corr[i] = corr;
        }
    }
}

// 32 blocks: per-block partial sums of {A, M, C, fix, noise} -> partials[b*5+c]
__global__ __launch_bounds__(256)
void partial_kernel(const float* __restrict__ y, const float* __restrict__ z,
                    const float* __restrict__ row_sd, const float* __restrict__ row_sm,
                    const float* __restrict__ row_corr, float* __restrict__ partials) {
    const int tid = threadIdx.x;
    const int i   = blockIdx.x * 256 + tid;
    float v[5];
    v[0] = row_sd[i];
    v[1] = row_sm[i];
    v[2] = row_corr[i];
    const float yv = y[i], zv = z[i];
    v[3] = fmaxf(yv - 1.f, 0.f) + fmaxf(-1.f - yv, 0.f)
         + fmaxf(zv - 1.f, 0.f) + fmaxf(-1.f - zv, 0.f);
    v[4] = 0.f;
    if (i < N - 2) {
        const float d2y = y[i + 2] - 2.f * y[i + 1] + y[i];
        const float d2z = z[i + 2] - 2.f * z[i + 1] + z[i];
        v[4] = d2y * d2y + d2z * d2z;
    }
    const int lane = tid & 63, wave = tid >> 6;
    __shared__ float s[4][5];
#pragma unroll
    for (int c = 0; c < 5; ++c) {
        float a = v[c];
#pragma unroll
        for (int off = 32; off; off >>= 1) a += __shfl_down(a, off);
        if (lane == 0) s[wave][c] = a;
    }
    __syncthreads();
    if (tid == 0) {
#pragma unroll
        for (int c = 0; c < 5; ++c)
            partials[blockIdx.x * 5 + c] = s[0][c] + s[1][c] + s[2][c] + s[3][c];
    }
}

// 1 block: final 32-way reduce + loss assembly
__global__ __launch_bounds__(64)
void final_kernel(const float* __restrict__ partials, float* __restrict__ out) {
    const int tid = threadIdx.x;
    float a[5] = {0.f, 0.f, 0.f, 0.f, 0.f};
    if (tid < 32) {
#pragma unroll
        for (int c = 0; c < 5; ++c) a[c] = partials[tid * 5 + c];
    }
#pragma unroll
    for (int c = 0; c < 5; ++c) {
#pragma unroll
        for (int off = 16; off; off >>= 1) a[c] += __shfl_down(a[c], off, 32);
    }
    if (tid == 0) {
        const float A = a[0], M = a[1], C = a[2], fix = a[3], noise = a[4];
        out[0] = fix + (2.f * A) / 10000.f
               + (2.f * (TRI - M) - (float)N - C) + 10.f * noise;
    }
}

extern "C" void kernel_launch(void* const* d_in, const int* in_sizes, int n_in,
                              void* d_out, int out_size, void* d_ws, size_t ws_size,
                              hipStream_t stream) {
    const float* x = (const float*)d_in[0];
    const float* y = (const float*)d_in[1];
    const float* z = (const float*)d_in[2];
    float* out      = (float*)d_out;
    float4* p4      = (float4*)d_ws;
    float* row_sd   = (float*)(p4 + N);
    float* row_sm   = row_sd + N;
    float* row_corr = row_sm + N;
    float* partials = row_corr + N;

    pack_kernel<<<N / 256, 256, 0, stream>>>(x, y, z, p4);
    main_kernel<<<2048, 256, 0, stream>>>(p4, row_sd, row_sm, row_corr);
    partial_kernel<<<32, 256, 0, stream>>>(y, z, row_sd, row_sm, row_corr, partials);
    final_kernel<<<1, 64, 0, stream>>>(partials, out);
}

// Round 12
// 31.143 us; speedup vs baseline: 2.4005x; 1.0862x over previous
//
#include <hip/hip_runtime.h>

constexpr int N = 8192;
// MIN_DIST = RADIUS*2*scale = 1.0f;  TRI = N(N+1)/2, exact in f32
constexpr float TRI = 33558528.0f;

__device__ __forceinline__ float fsqrt(float v) { return __builtin_amdgcn_sqrtf(v); }
__device__ __forceinline__ float sgpr(float v) {
    return __int_as_float(__builtin_amdgcn_readfirstlane(__float_as_int(v)));
}

// ws layout: p4[N] (float4) | row_sd[N] | row_sm[N] | row_corr[N] | partials[32*5]

__global__ __launch_bounds__(256)
void pack_kernel(const float* __restrict__ x, const float* __restrict__ y,
                 const float* __restrict__ z, float4* __restrict__ p4) {
    const int i = blockIdx.x * 256 + threadIdx.x;
    p4[i] = make_float4(x[i], y[i], z[i], 0.f);
}

// 2048 blocks:
//  [0,1024):    pair tiles — rows {4b..4b+3} (top) + {N-4b-4..N-4b-1} (bot).
//               SINGLE union sweep j in [topBase&~255, N): top rows always
//               active, bot rows activate at botBase. Row coords pinned to
//               SGPRs (readfirstlane) so the float4 preload stays in VGPRs.
//  [1024,2048): masked-prefix-run correction (R7 structure).
__global__ __launch_bounds__(256, 8)
void main_kernel(const float4* __restrict__ p4,
                 float* __restrict__ row_sd, float* __restrict__ row_sm,
                 float* __restrict__ row_corr) {
    const int tid  = threadIdx.x;
    const int lane = tid & 63;
    const int wave = tid >> 6;

    if (blockIdx.x < 1024) {
        const int b       = blockIdx.x;
        const int topBase = 4 * b;            // 0..4092
        const int botBase = N - 4 * (b + 1);  // 8188..4096

        // Row coordinates -> SGPRs (block-uniform, exact).
        float xr[8], yr[8], zr[8];
#pragma unroll
        for (int r = 0; r < 4; ++r) {
            const float4 pt = p4[topBase + r];
            const float4 pb = p4[botBase + r];
            xr[r]     = sgpr(pt.x); yr[r]     = sgpr(pt.y); zr[r]     = sgpr(pt.z);
            xr[4 + r] = sgpr(pb.x); yr[4 + r] = sgpr(pb.y); zr[4 + r] = sgpr(pb.z);
        }
        float sd[8], sm[8];
#pragma unroll
        for (int r = 0; r < 8; ++r) { sd[r] = 0.f; sm[r] = 0.f; }

        const int cstart = topBase & ~255;
        float4 p = p4[cstart + tid];
        for (int c = cstart; c < N; c += 256) {
            const float4 cur = p;
            if (c + 256 < N) p = p4[c + 256 + tid];
            const int  j       = c + tid;
            const bool botAct  = (c + 256 > botBase);
            const bool topPred = (c < topBase + 4);
            const bool botPred = botAct && (c < botBase + 4);

            if (topPred || botPred) {
                // predicated chunks (<=3 per block)
#pragma unroll
                for (int r = 0; r < 4; ++r) {
                    const float dx = cur.x - xr[r], dy = cur.y - yr[r], dz = cur.z - zr[r];
                    const float d  = fsqrt(dx * dx + dy * dy + dz * dz);
                    if (j >= topBase + r) { sd[r] += d; sm[r] += fminf(d, 1.f); }
                }
                if (botAct) {
#pragma unroll
                    for (int r = 0; r < 4; ++r) {
                        const float dx = cur.x - xr[4 + r], dy = cur.y - yr[4 + r], dz = cur.z - zr[4 + r];
                        const float d  = fsqrt(dx * dx + dy * dy + dz * dz);
                        if (j >= botBase + r) { sd[4 + r] += d; sm[4 + r] += fminf(d, 1.f); }
                    }
                }
            } else {
#pragma unroll
                for (int r = 0; r < 4; ++r) {
                    const float dx = cur.x - xr[r], dy = cur.y - yr[r], dz = cur.z - zr[r];
                    const float d  = fsqrt(dx * dx + dy * dy + dz * dz);
                    sd[r] += d; sm[r] += fminf(d, 1.f);
                }
                if (botAct) {
#pragma unroll
                    for (int r = 0; r < 4; ++r) {
                        const float dx = cur.x - xr[4 + r], dy = cur.y - yr[4 + r], dz = cur.z - zr[4 + r];
                        const float d  = fsqrt(dx * dx + dy * dy + dz * dz);
                        sd[4 + r] += d; sm[4 + r] += fminf(d, 1.f);
                    }
                }
            }
        }

        // reduce 8 rows across the block
        __shared__ float lsd[4][8];
        __shared__ float lsm[4][8];
#pragma unroll
        for (int r = 0; r < 8; ++r) {
            float a = sd[r], c = sm[r];
#pragma unroll
            for (int off = 32; off; off >>= 1) {
                a += __shfl_down(a, off);
                c += __shfl_down(c, off);
            }
            if (lane == 0) { lsd[wave][r] = a; lsm[wave][r] = c; }
        }
        __syncthreads();
        if (tid < 8) {
            const float a = lsd[0][tid] + lsd[1][tid] + lsd[2][tid] + lsd[3][tid];
            const float c = lsm[0][tid] + lsm[1][tid] + lsm[2][tid] + lsm[3][tid];
            const int   i = (tid < 4) ? (topBase + tid) : (botBase + tid - 4);
            row_sd[i] = a;
            row_sm[i] = c;
        }
    } else {
        // corr: 8 rows/block, 2 rows/wave, 128-j windows, speculative preload
        const int cb = blockIdx.x - 1024;
#pragma unroll
        for (int rr = 0; rr < 2; ++rr) {
            const int    i  = 8 * cb + 2 * wave + rr;
            const float4 pi = p4[i];
            float corr = 0.f;
            int   jb   = i;
            float4 a  = p4[min(jb + lane,      N - 1)];
            float4 bq = p4[min(jb + 64 + lane, N - 1)];
            while (true) {
                const float4 na = p4[min(jb + 128 + lane, N - 1)];
                const float4 nb = p4[min(jb + 192 + lane, N - 1)];
                const int j0i = jb + lane, j1i = jb + 64 + lane;
                float dx = a.x - pi.x, dy = a.y - pi.y, dz = a.z - pi.z;
                const float d0 = fsqrt(dx * dx + dy * dy + dz * dz);
                dx = bq.x - pi.x; dy = bq.y - pi.y; dz = bq.z - pi.z;
                const float d1 = fsqrt(dx * dx + dy * dy + dz * dz);
                const unsigned long long m0 = __ballot(j0i >= N || d0 > 1.f);
                const unsigned long long m1 = __ballot(j1i >= N || d1 > 1.f);
                int stop;
                if (m0)      stop = __builtin_ctzll(m0);
                else if (m1) stop = 64 + __builtin_ctzll(m1);
                else         stop = 128;
                if (lane < stop)      corr += 1.f - d0;
                if (64 + lane < stop) corr += 1.f - d1;
                if (stop < 128) break;
                jb += 128;
                a = na; bq = nb;
            }
#pragma unroll
            for (int off = 32; off; off >>= 1) corr += __shfl_down(corr, off);
            if (lane == 0) row_corr[i] = corr;
        }
    }
}

// 32 blocks: per-block partial sums of {A, M, C, fix, noise} -> partials[b*5+c]
__global__ __launch_bounds__(256)
void partial_kernel(const float* __restrict__ y, const float* __restrict__ z,
                    const float* __restrict__ row_sd, const float* __restrict__ row_sm,
                    const float* __restrict__ row_corr, float* __restrict__ partials) {
    const int tid = threadIdx.x;
    const int i   = blockIdx.x * 256 + tid;
    float v[5];
    v[0] = row_sd[i];
    v[1] = row_sm[i];
    v[2] = row_corr[i];
    const float yv = y[i], zv = z[i];
    v[3] = fmaxf(yv - 1.f, 0.f) + fmaxf(-1.f - yv, 0.f)
         + fmaxf(zv - 1.f, 0.f) + fmaxf(-1.f - zv, 0.f);
    v[4] = 0.f;
    if (i < N - 2) {
        const float d2y = y[i + 2] - 2.f * y[i + 1] + y[i];
        const float d2z = z[i + 2] - 2.f * z[i + 1] + z[i];
        v[4] = d2y * d2y + d2z * d2z;
    }
    const int lane = tid & 63, wave = tid >> 6;
    __shared__ float s[4][5];
#pragma unroll
    for (int c = 0; c < 5; ++c) {
        float a = v[c];
#pragma unroll
        for (int off = 32; off; off >>= 1) a += __shfl_down(a, off);
        if (lane == 0) s[wave][c] = a;
    }
    __syncthreads();
    if (tid == 0) {
#pragma unroll
        for (int c = 0; c < 5; ++c)
            partials[blockIdx.x * 5 + c] = s[0][c] + s[1][c] + s[2][c] + s[3][c];
    }
}

// 1 block: final 32-way reduce + loss assembly
__global__ __launch_bounds__(64)
void final_kernel(const float* __restrict__ partials, float* __restrict__ out) {
    const int tid = threadIdx.x;
    float a[5] = {0.f, 0.f, 0.f, 0.f, 0.f};
    if (tid < 32) {
#pragma unroll
        for (int c = 0; c < 5; ++c) a[c] = partials[tid * 5 + c];
    }
#pragma unroll
    for (int c = 0; c < 5; ++c) {
#pragma unroll
        for (int off = 16; off; off >>= 1) a[c] += __shfl_down(a[c], off, 32);
    }
    if (tid == 0) {
        const float A = a[0], M = a[1], C = a[2], fix = a[3], noise = a[4];
        out[0] = fix + (2.f * A) / 10000.f
               + (2.f * (TRI - M) - (float)N - C) + 10.f * noise;
    }
}

extern "C" void kernel_launch(void* const* d_in, const int* in_sizes, int n_in,
                              void* d_out, int out_size, void* d_ws, size_t ws_size,
                              hipStream_t stream) {
    const float* x = (const float*)d_in[0];
    const float* y = (const float*)d_in[1];
    const float* z = (const float*)d_in[2];
    float* out      = (float*)d_out;
    float4* p4      = (float4*)d_ws;
    float* row_sd   = (float*)(p4 + N);
    float* row_sm   = row_sd + N;
    float* row_corr = row_sm + N;
    float* partials = row_corr + N;

    pack_kernel<<<N / 256, 256, 0, stream>>>(x, y, z, p4);
    main_kernel<<<2048, 256, 0, stream>>>(p4, row_sd, row_sm, row_corr);
    partial_kernel<<<32, 256, 0, stream>>>(y, z, row_sd, row_sm, row_corr, partials);
    final_kernel<<<1, 64, 0, stream>>>(partials, out);
}